// Round 3
// baseline (1193.297 us; speedup 1.0000x reference)
//
#include <hip/hip_runtime.h>
#include <cstdint>

#define B_ 64
#define N_ 512
#define D_ 256
#define L_ 4

typedef __bf16 bf16;
typedef __attribute__((ext_vector_type(8))) __bf16 bf16x8;
typedef __attribute__((ext_vector_type(4))) __bf16 bf16x4;
typedef __attribute__((ext_vector_type(4))) float f32x4;

#define MFMA16(a, b, c) __builtin_amdgcn_mfma_f32_16x16x32_bf16((a), (b), (c), 0, 0, 0)

__device__ __forceinline__ void async_copy16(void* lds, const void* glb) {
  __builtin_amdgcn_global_load_lds(
      (const __attribute__((address_space(1))) void*)glb,
      (__attribute__((address_space(3))) void*)lds, 16, 0, 0);
}

__device__ __forceinline__ float sigmoidf_(float z) {
  return 1.0f / (1.0f + __expf(-z));
}

// ---------------------------------------------------------------------------
// Generic bf16 GEMM:  C[m][n] = sum_k A[m][k] * Bm[n][k]   (A * Bm^T)
// BM=BN=128, BK=32; 4 waves, each a 64x64 quadrant (4x4 MFMA tiles).
// grid = (Nout/128, M/128, nbatch)
// ---------------------------------------------------------------------------
__global__ __launch_bounds__(256, 2) void gemm_bt(
    const bf16* __restrict__ A, const bf16* __restrict__ Bm,
    const float* __restrict__ bias, const float* __restrict__ resid,
    float* __restrict__ outF, bf16* __restrict__ outB, bf16* __restrict__ outT,
    int M, int K, int lda, int ldb, int ldc,
    long long sA, long long sB, long long sC, int relu)
{
  __shared__ bf16 As[128 * 32];
  __shared__ bf16 Bs[128 * 32];
  const int tid = threadIdx.x;
  const int w = tid >> 6, lane = tid & 63;
  const int l16 = lane & 15, quad = lane >> 4;
  const int wm = w & 1, wn = w >> 1;
  const int bx = blockIdx.x, by = blockIdx.y, bz = blockIdx.z;
  A  += (size_t)bz * sA;
  Bm += (size_t)bz * sB;
  const size_t cofs = (size_t)bz * sC;

  f32x4 acc[4][4] = {};

  const int arow = lane >> 2;
  const int acg  = (lane & 3) ^ ((lane >> 3) & 3);
  const int sw   = (quad ^ ((l16 >> 1) & 3)) << 3;

  const int nk = K >> 5;
  for (int kc = 0; kc < nk; ++kc) {
    const int k0 = kc << 5;
#pragma unroll
    for (int r = 0; r < 2; ++r) {
      const int c = w + (r << 2);
      const int row = (c << 4) + arow;
      async_copy16(&As[c * 512],
                   A + (size_t)(by * 128 + row) * lda + k0 + (acg << 3));
      async_copy16(&Bs[c * 512],
                   Bm + (size_t)(bx * 128 + row) * ldb + k0 + (acg << 3));
    }
    __syncthreads();
    bf16x8 af[4], bfv[4];
#pragma unroll
    for (int i = 0; i < 4; ++i) {
      af[i]  = *(const bf16x8*)&As[(wm * 64 + i * 16 + l16) * 32 + sw];
      bfv[i] = *(const bf16x8*)&Bs[(wn * 64 + i * 16 + l16) * 32 + sw];
    }
#pragma unroll
    for (int i = 0; i < 4; ++i)
#pragma unroll
      for (int j = 0; j < 4; ++j)
        acc[i][j] = MFMA16(af[i], bfv[j], acc[i][j]);
    __syncthreads();
  }

  const int rbase = by * 128 + wm * 64 + (quad << 2);
  const int cbase = bx * 128 + wn * 64 + l16;
#pragma unroll
  for (int j = 0; j < 4; ++j) {
    const int col = cbase + j * 16;
    const float bv = bias ? bias[col] : 0.0f;
#pragma unroll
    for (int i = 0; i < 4; ++i) {
      const int r0 = rbase + i * 16;
      float v[4];
#pragma unroll
      for (int r = 0; r < 4; ++r) {
        float t = acc[i][j][r] + bv;
        if (relu) t = fmaxf(t, 0.0f);
        if (resid) t += resid[cofs + (size_t)(r0 + r) * ldc + col];
        v[r] = t;
      }
      if (outF) {
#pragma unroll
        for (int r = 0; r < 4; ++r)
          outF[cofs + (size_t)(r0 + r) * ldc + col] = v[r];
      }
      if (outB) {
#pragma unroll
        for (int r = 0; r < 4; ++r)
          outB[cofs + (size_t)(r0 + r) * ldc + col] = (bf16)v[r];
      }
      if (outT) {
        bf16x4 tv;
#pragma unroll
        for (int r = 0; r < 4; ++r) tv[r] = (bf16)v[r];
        *(bf16x4*)&outT[((size_t)(r0 >> 9)) * (D_ * N_) + (size_t)col * N_ +
                        (r0 & (N_ - 1))] = tv;
      }
    }
  }
}

// ---------------------------------------------------------------------------
// qk_attn: batched 512x512 (K=256) GEMM  P = sigmoid(q @ xb^T), diag/adj mask.
// Writes UNNORMALIZED P (f32) into outA and per-row partial sums into
// partial[b][row][bx*2+wn] (8 slots per row, fully written -> no init needed).
// grid = (N/128, N/128, B)
// ---------------------------------------------------------------------------
__global__ __launch_bounds__(256, 2) void qk_attn(
    const bf16* __restrict__ q, const bf16* __restrict__ xb,
    const float* __restrict__ adj, float* __restrict__ outA,
    float* __restrict__ partial)
{
  __shared__ bf16 As[128 * 32];
  __shared__ bf16 Bs[128 * 32];
  const int tid = threadIdx.x;
  const int w = tid >> 6, lane = tid & 63;
  const int l16 = lane & 15, quad = lane >> 4;
  const int wm = w & 1, wn = w >> 1;
  const int bx = blockIdx.x, by = blockIdx.y, bz = blockIdx.z;
  const bf16* Aq = q  + (size_t)bz * N_ * D_;
  const bf16* Bx = xb + (size_t)bz * N_ * D_;

  f32x4 acc[4][4] = {};
  const int arow = lane >> 2;
  const int acg  = (lane & 3) ^ ((lane >> 3) & 3);
  const int sw   = (quad ^ ((l16 >> 1) & 3)) << 3;

#pragma unroll
  for (int kc = 0; kc < 8; ++kc) {
    const int k0 = kc << 5;
#pragma unroll
    for (int r = 0; r < 2; ++r) {
      const int c = w + (r << 2);
      const int row = (c << 4) + arow;
      async_copy16(&As[c * 512], Aq + (size_t)(by * 128 + row) * D_ + k0 + (acg << 3));
      async_copy16(&Bs[c * 512], Bx + (size_t)(bx * 128 + row) * D_ + k0 + (acg << 3));
    }
    __syncthreads();
    bf16x8 af[4], bfv[4];
#pragma unroll
    for (int i = 0; i < 4; ++i) {
      af[i]  = *(const bf16x8*)&As[(wm * 64 + i * 16 + l16) * 32 + sw];
      bfv[i] = *(const bf16x8*)&Bs[(wn * 64 + i * 16 + l16) * 32 + sw];
    }
#pragma unroll
    for (int i = 0; i < 4; ++i)
#pragma unroll
      for (int j = 0; j < 4; ++j)
        acc[i][j] = MFMA16(af[i], bfv[j], acc[i][j]);
    __syncthreads();
  }

  // epilogue: sigmoid + diag + adjacency mask; partial row sums
  const int rbase = by * 128 + wm * 64 + (quad << 2);
  const int cbase = bx * 128 + wn * 64 + l16;
  const size_t abase = (size_t)bz * N_ * N_;
  float p[4][4] = {};   // [i][r] partial row sums over this wave's 64 cols
#pragma unroll
  for (int j = 0; j < 4; ++j) {
    const int col = cbase + j * 16;
#pragma unroll
    for (int i = 0; i < 4; ++i) {
#pragma unroll
      for (int r = 0; r < 4; ++r) {
        const int row = rbase + i * 16 + r;
        const float sg = sigmoidf_(acc[i][j][r]);
        float v;
        if (row == col) v = sg + 1e-5f;
        else            v = sg * adj[abase + (size_t)row * N_ + col];
        outA[abase + (size_t)row * N_ + col] = v;
        p[i][r] += v;
      }
    }
  }
  // reduce over the 16 l16-lanes (bits 0..3 of lane id)
#pragma unroll
  for (int i = 0; i < 4; ++i)
#pragma unroll
    for (int r = 0; r < 4; ++r) {
#pragma unroll
      for (int m = 1; m < 16; m <<= 1) p[i][r] += __shfl_xor(p[i][r], m, 64);
    }
  if (l16 == 0) {
#pragma unroll
    for (int i = 0; i < 4; ++i)
#pragma unroll
      for (int r = 0; r < 4; ++r) {
        const int row = rbase + i * 16 + r;
        partial[(((size_t)bz * N_ + row) << 3) + bx * 2 + wn] = p[i][r];
      }
  }
}

// ---------------------------------------------------------------------------
// attn_norm: per 16 global rows: rinv = 1/sum(partial[0..8)); in-place
// outA *= rinv; Sb = bf16(outA). grid = B*N/16, 256 threads, float4 path.
// ---------------------------------------------------------------------------
__global__ __launch_bounds__(256) void attn_norm(
    float* __restrict__ outA, const float* __restrict__ partial,
    bf16* __restrict__ Sb)
{
  __shared__ float lr[16];
  const int tid = threadIdx.x;
  const size_t row0 = (size_t)blockIdx.x * 16;
  if (tid < 16) {
    const float* pp = partial + ((row0 + tid) << 3);
    float s = 0.f;
#pragma unroll
    for (int k = 0; k < 8; ++k) s += pp[k];
    lr[tid] = 1.0f / s;
  }
  __syncthreads();
  const size_t base4 = row0 * N_ / 4;
#pragma unroll
  for (int e = 0; e < 8; ++e) {
    const int idx = tid + e * 256;          // float4 index within 16 rows
    const int r = idx >> 7;                 // 128 float4 per row
    const float s = lr[r];
    float4 v = ((const float4*)outA)[base4 + idx];
    v.x *= s; v.y *= s; v.z *= s; v.w *= s;
    ((float4*)outA)[base4 + idx] = v;
    bf16x4 o;
    o[0] = (bf16)v.x; o[1] = (bf16)v.y; o[2] = (bf16)v.z; o[3] = (bf16)v.w;
    ((bf16x4*)Sb)[base4 + idx] = o;
  }
}

// ---------------------------------------------------------------------------
// init: x -> out_x (f32 master), x_bf16, xT_bf16 (LDS 32x32 transpose)
// ---------------------------------------------------------------------------
__global__ __launch_bounds__(256) void init_x(
    const float* __restrict__ x, float* __restrict__ outX,
    bf16* __restrict__ xb, bf16* __restrict__ xT)
{
  __shared__ float t[32 * 33];
  const int tid = threadIdx.x;
  const int nt = blockIdx.x, dt = blockIdx.y, b = blockIdx.z;
#pragma unroll
  for (int e = 0; e < 4; ++e) {
    const int idx = tid + e * 256;
    const int r = idx >> 5, c = idx & 31;
    const size_t g = ((size_t)(b * N_ + nt * 32 + r)) * D_ + dt * 32 + c;
    const float v = x[g];
    outX[g] = v;
    xb[g] = (bf16)v;
    t[r * 33 + c] = v;
  }
  __syncthreads();
#pragma unroll
  for (int e = 0; e < 4; ++e) {
    const int idx = tid + e * 256;
    const int r = idx >> 5, c = idx & 31;
    xT[((size_t)(b * D_ + dt * 32 + r)) * N_ + nt * 32 + c] = (bf16)t[c * 33 + r];
  }
}

__global__ __launch_bounds__(256) void cvt_bf16(
    const float* __restrict__ src, bf16* __restrict__ dst, int n4)
{
  const int i = blockIdx.x * 256 + threadIdx.x;
  if (i < n4) {
    const float4 v = ((const float4*)src)[i];
    bf16x4 o;
    o[0] = (bf16)v.x; o[1] = (bf16)v.y; o[2] = (bf16)v.z; o[3] = (bf16)v.w;
    ((bf16x4*)dst)[i] = o;
  }
}

extern "C" void kernel_launch(void* const* d_in, const int* in_sizes, int n_in,
                              void* d_out, int out_size, void* d_ws, size_t ws_size,
                              hipStream_t stream)
{
  const float* x_in  = (const float*)d_in[0];
  const float* adj   = (const float*)d_in[1];
  const float* wattn = (const float*)d_in[2];
  const float* battn = (const float*)d_in[3];
  const float* w0    = (const float*)d_in[4];
  const float* b0    = (const float*)d_in[5];
  const float* w1    = (const float*)d_in[6];
  const float* b1    = (const float*)d_in[7];
  const float* wf    = (const float*)d_in[8];
  const float* bfin  = (const float*)d_in[9];

  float* out_x    = (float*)d_out;                     // [B,N,D] f32 master
  float* out_attn = out_x + (size_t)B_ * N_ * D_;      // [L,B,N,N]

  bf16* wb = (bf16*)d_ws;                              // 13 * D*D weights
  bf16* xb = wb + 13 * (D_ * D_);                      // [B,N,D] bf16
  bf16* xT = xb + (size_t)B_ * N_ * D_;                // [B,D,N] bf16
  bf16* qb = xT + (size_t)B_ * N_ * D_;                // q / x'
  bf16* hb = qb + (size_t)B_ * N_ * D_;                // lin0 output
  bf16* Sb = hb + (size_t)B_ * N_ * D_;                // [B,N,N] normalized S
  float* partial = (float*)(Sb + (size_t)B_ * N_ * N_); // [B,N,8] row partials

  const int DD2 = D_ * D_;
  const int Mfull = B_ * N_;  // 32768

  cvt_bf16<<<dim3((L_ * DD2 / 4 + 255) / 256), 256, 0, stream>>>(wattn, wb, L_ * DD2 / 4);
  cvt_bf16<<<dim3((L_ * DD2 / 4 + 255) / 256), 256, 0, stream>>>(w0, wb + 4 * DD2, L_ * DD2 / 4);
  cvt_bf16<<<dim3((L_ * DD2 / 4 + 255) / 256), 256, 0, stream>>>(w1, wb + 8 * DD2, L_ * DD2 / 4);
  cvt_bf16<<<dim3((DD2 / 4 + 255) / 256), 256, 0, stream>>>(wf, wb + 12 * DD2, DD2 / 4);

  init_x<<<dim3(N_ / 32, D_ / 32, B_), 256, 0, stream>>>(x_in, out_x, xb, xT);

  for (int l = 0; l < L_; ++l) {
    float* outA = out_attn + (size_t)l * B_ * N_ * N_;
    // q = x @ Wattn^T + b
    gemm_bt<<<dim3(2, Mfull / 128, 1), 256, 0, stream>>>(
        xb, wb + l * DD2, battn + l * D_, nullptr,
        nullptr, qb, nullptr,
        Mfull, D_, D_, D_, D_, 0, 0, 0, 0);
    // P = sigmoid(q @ x^T) masked (unnormalized, f32) + row partials
    qk_attn<<<dim3(N_ / 128, N_ / 128, B_), 256, 0, stream>>>(
        qb, xb, adj, outA, partial);
    // normalize in place; emit bf16 S
    attn_norm<<<dim3(Mfull / 16), 256, 0, stream>>>(outA, partial, Sb);
    // x' = S @ x  (batched; B = xT rows) -> qb
    gemm_bt<<<dim3(2, N_ / 128, B_), 256, 0, stream>>>(
        Sb, xT, nullptr, nullptr,
        nullptr, qb, nullptr,
        N_, N_, N_, N_, D_,
        (long long)N_ * N_, (long long)D_ * N_, (long long)N_ * D_, 0);
    // h = relu(x' @ W0^T + b0)
    gemm_bt<<<dim3(2, Mfull / 128, 1), 256, 0, stream>>>(
        qb, wb + (4 + l) * DD2, b0 + l * D_, nullptr,
        nullptr, hb, nullptr,
        Mfull, D_, D_, D_, D_, 0, 0, 0, 1);
    // x = relu(h @ W1^T + b1) + x0 -> out_x (f32), xb, xT
    gemm_bt<<<dim3(2, Mfull / 128, 1), 256, 0, stream>>>(
        hb, wb + (8 + l) * DD2, b1 + l * D_, out_x,
        out_x, xb, xT,
        Mfull, D_, D_, D_, D_, 0, 0, 0, 1);
  }
  gemm_bt<<<dim3(2, Mfull / 128, 1), 256, 0, stream>>>(
      xb, wb + 12 * DD2, bfin, nullptr,
      out_x, nullptr, nullptr,
      Mfull, D_, D_, D_, D_, 0, 0, 0, 0);
}

// Round 4
// 1075.924 us; speedup vs baseline: 1.1091x; 1.1091x over previous
//
#include <hip/hip_runtime.h>
#include <cstdint>

#define B_ 64
#define N_ 512
#define D_ 256
#define L_ 4

typedef __bf16 bf16;
typedef __attribute__((ext_vector_type(8))) __bf16 bf16x8;
typedef __attribute__((ext_vector_type(4))) __bf16 bf16x4;
typedef __attribute__((ext_vector_type(4))) float f32x4;

#define MFMA16(a, b, c) __builtin_amdgcn_mfma_f32_16x16x32_bf16((a), (b), (c), 0, 0, 0)

__device__ __forceinline__ float sigmoidf_(float z) {
  return 1.0f / (1.0f + __expf(-z));
}

// ---------------------------------------------------------------------------
// attn_layer: one block per (32-row strip, batch). 256 thr = 4 waves.
// Phase 0: q = x_strip @ Wa^T + ba          (A from LDS, B=Wa streamed from L2)
// Phase 1: P = sigmoid(q @ xb^T) masked     (unnormalized, bf16 in LDS)
// Phase 2: rowsum -> normalize; attls f32 out; normalized P back to LDS
// Phase 3: x' = P @ x  (B = xT streamed)    -> qout bf16
// LDS ~51 KB -> 3 blocks/CU.
// ---------------------------------------------------------------------------
__global__ __launch_bounds__(256, 3) void attn_layer(
    const bf16* __restrict__ xb, const bf16* __restrict__ xT,
    const bf16* __restrict__ Wa, const float* __restrict__ ba,
    const float* __restrict__ adj, float* __restrict__ outA,
    bf16* __restrict__ qout)
{
  __shared__ bf16 qs[32 * 264];     // q strip (A-layout), stride 264
  __shared__ bf16 xps[32 * 520];    // phase0: x strip (stride 264); then P (stride 520)
  __shared__ float psum[4][32];
  __shared__ float rinvs[32];

  const int tid = threadIdx.x, w = tid >> 6, lane = tid & 63;
  const int l16 = lane & 15, quad = lane >> 4;
  const int row0 = blockIdx.x * 32, b = blockIdx.y;

  // ---- load x strip [32][256] into xps (stride 264) ----
#pragma unroll
  for (int e = 0; e < 4; ++e) {
    const int cc = tid + e * 256;
    const int r = cc >> 5, cg = cc & 31;
    *(bf16x8*)&xps[r * 264 + cg * 8] =
        *(const bf16x8*)(xb + ((size_t)(b * N_ + row0 + r)) * D_ + cg * 8);
  }
  __syncthreads();

  // ---- phase 0: q = x @ Wa^T + ba ; wave w -> cols [64w, 64w+64) ----
  {
    f32x4 acc0[2][4] = {};
#pragma unroll
    for (int ks = 0; ks < 8; ++ks) {
      bf16x8 af[2];
#pragma unroll
      for (int m = 0; m < 2; ++m)
        af[m] = *(const bf16x8*)&xps[(16 * m + l16) * 264 + ks * 32 + quad * 8];
      bf16x8 bw[4];
#pragma unroll
      for (int i = 0; i < 4; ++i) {
        const int col = 64 * w + 16 * i + l16;
        bw[i] = *(const bf16x8*)(Wa + (size_t)col * D_ + ks * 32 + quad * 8);
      }
#pragma unroll
      for (int m = 0; m < 2; ++m)
#pragma unroll
        for (int i = 0; i < 4; ++i) acc0[m][i] = MFMA16(af[m], bw[i], acc0[m][i]);
    }
#pragma unroll
    for (int m = 0; m < 2; ++m)
#pragma unroll
      for (int i = 0; i < 4; ++i) {
        const int col = 64 * w + 16 * i + l16;
        const float bv = ba[col];
#pragma unroll
        for (int r = 0; r < 4; ++r)
          qs[(16 * m + quad * 4 + r) * 264 + col] = (bf16)(acc0[m][i][r] + bv);
      }
  }
  __syncthreads();   // qs ready; xs (xps) dead -> becomes P

  // ---- phase 1: P = sigmoid(q @ xb^T), diag/adj mask -> xps bf16 ----
  float p[2][4] = {};
  for (int ct = 0; ct < 4; ++ct) {
    f32x4 acc1[2][2] = {};
#pragma unroll
    for (int ks = 0; ks < 8; ++ks) {
      bf16x8 af[2];
#pragma unroll
      for (int m = 0; m < 2; ++m)
        af[m] = *(const bf16x8*)&qs[(16 * m + l16) * 264 + ks * 32 + quad * 8];
      bf16x8 bx[2];
#pragma unroll
      for (int jt = 0; jt < 2; ++jt) {
        const int gcol = ct * 128 + w * 32 + jt * 16 + l16;
        bx[jt] = *(const bf16x8*)(xb + ((size_t)(b * N_ + gcol)) * D_ + ks * 32 + quad * 8);
      }
#pragma unroll
      for (int m = 0; m < 2; ++m)
#pragma unroll
        for (int jt = 0; jt < 2; ++jt)
          acc1[m][jt] = MFMA16(af[m], bx[jt], acc1[m][jt]);
    }
#pragma unroll
    for (int jt = 0; jt < 2; ++jt) {
      const int lcol = ct * 128 + w * 32 + jt * 16 + l16;
#pragma unroll
      for (int m = 0; m < 2; ++m)
#pragma unroll
        for (int r = 0; r < 4; ++r) {
          const int row = 16 * m + quad * 4 + r;
          const int grow = row0 + row;
          const float sg = sigmoidf_(acc1[m][jt][r]);
          float v;
          if (grow == lcol) v = sg + 1e-5f;
          else              v = sg * adj[((size_t)b * N_ + grow) * N_ + lcol];
          const bf16 bv = (bf16)v;
          xps[row * 520 + lcol] = bv;
          p[m][r] += (float)bv;
        }
    }
  }
  // reduce partial sums over the 16 l16-lanes
#pragma unroll
  for (int m = 0; m < 2; ++m)
#pragma unroll
    for (int r = 0; r < 4; ++r) {
#pragma unroll
      for (int msk = 1; msk < 16; msk <<= 1) p[m][r] += __shfl_xor(p[m][r], msk, 64);
    }
  if (l16 == 0) {
#pragma unroll
    for (int m = 0; m < 2; ++m)
#pragma unroll
      for (int r = 0; r < 4; ++r) psum[w][16 * m + quad * 4 + r] = p[m][r];
  }
  __syncthreads();
  if (tid < 32)
    rinvs[tid] = 1.0f / (psum[0][tid] + psum[1][tid] + psum[2][tid] + psum[3][tid]);
  __syncthreads();

  // ---- phase 2: normalize; attls f32 out; normalized bf16 back to xps ----
  const size_t abase = ((size_t)b * N_ + row0) * N_;
#pragma unroll
  for (int e = 0; e < 16; ++e) {
    const int idx = tid + e * 256;          // vec4 index
    const int row = idx >> 7, c4 = (idx & 127) * 4;
    const float ri = rinvs[row];
    bf16x4 pv = *(const bf16x4*)&xps[row * 520 + c4];
    float4 nv;
    nv.x = (float)pv[0] * ri; nv.y = (float)pv[1] * ri;
    nv.z = (float)pv[2] * ri; nv.w = (float)pv[3] * ri;
    *(float4*)&outA[abase + (size_t)row * N_ + c4] = nv;
    bf16x4 o;
    o[0] = (bf16)nv.x; o[1] = (bf16)nv.y; o[2] = (bf16)nv.z; o[3] = (bf16)nv.w;
    *(bf16x4*)&xps[row * 520 + c4] = o;
  }
  __syncthreads();

  // ---- phase 3: x' = P @ x  (B = xT rows streamed), K = 512 ----
  f32x4 acc3[2][4] = {};
#pragma unroll
  for (int ks = 0; ks < 16; ++ks) {
    bf16x8 af[2];
#pragma unroll
    for (int m = 0; m < 2; ++m)
      af[m] = *(const bf16x8*)&xps[(16 * m + l16) * 520 + ks * 32 + quad * 8];
    bf16x8 bt[4];
#pragma unroll
    for (int i = 0; i < 4; ++i) {
      const int d = 64 * w + 16 * i + l16;
      bt[i] = *(const bf16x8*)(xT + ((size_t)(b * D_ + d)) * N_ + ks * 32 + quad * 8);
    }
#pragma unroll
    for (int m = 0; m < 2; ++m)
#pragma unroll
      for (int i = 0; i < 4; ++i) acc3[m][i] = MFMA16(af[m], bt[i], acc3[m][i]);
  }
#pragma unroll
  for (int m = 0; m < 2; ++m)
#pragma unroll
    for (int i = 0; i < 4; ++i) {
      const int d = 64 * w + 16 * i + l16;
#pragma unroll
      for (int r = 0; r < 4; ++r) {
        const int grow = row0 + 16 * m + quad * 4 + r;
        qout[((size_t)(b * N_ + grow)) * D_ + d] = (bf16)acc3[m][i][r];
      }
    }
}

// ---------------------------------------------------------------------------
// ffn_block: per 32-row strip: h = relu(x'@W0^T+b0) (LDS); x = relu(h@W1^T+b1)
// + resid; writes out_x f32 (in-place resid), xb bf16, xT bf16 transposed.
// B-operands streamed from L2. grid = B*N/32 = 1024, 256 thr, ~4 blocks/CU.
// ---------------------------------------------------------------------------
__global__ __launch_bounds__(256, 4) void ffn_block(
    const bf16* __restrict__ qin, const bf16* __restrict__ W0,
    const float* __restrict__ b0, const bf16* __restrict__ W1,
    const float* __restrict__ b1, float* __restrict__ outX,
    bf16* __restrict__ xbo, bf16* __restrict__ xTo)
{
  __shared__ bf16 as_[32 * 264];
  __shared__ bf16 hs[32 * 264];
  const int tid = threadIdx.x, w = tid >> 6, lane = tid & 63;
  const int l16 = lane & 15, quad = lane >> 4;
  const int row0g = blockIdx.x * 32;
  const int b = row0g >> 9, node0 = row0g & (N_ - 1);

  // stage x' strip
#pragma unroll
  for (int e = 0; e < 4; ++e) {
    const int cc = tid + e * 256;
    const int r = cc >> 5, cg = cc & 31;
    *(bf16x8*)&as_[r * 264 + cg * 8] =
        *(const bf16x8*)(qin + ((size_t)(row0g + r)) * D_ + cg * 8);
  }
  __syncthreads();

  // stage 1: h = relu(x' @ W0^T + b0) -> hs
  {
    f32x4 acc[2][4] = {};
#pragma unroll
    for (int ks = 0; ks < 8; ++ks) {
      bf16x8 af[2];
#pragma unroll
      for (int m = 0; m < 2; ++m)
        af[m] = *(const bf16x8*)&as_[(16 * m + l16) * 264 + ks * 32 + quad * 8];
      bf16x8 bw[4];
#pragma unroll
      for (int i = 0; i < 4; ++i) {
        const int col = 64 * w + 16 * i + l16;
        bw[i] = *(const bf16x8*)(W0 + (size_t)col * D_ + ks * 32 + quad * 8);
      }
#pragma unroll
      for (int m = 0; m < 2; ++m)
#pragma unroll
        for (int i = 0; i < 4; ++i) acc[m][i] = MFMA16(af[m], bw[i], acc[m][i]);
    }
#pragma unroll
    for (int m = 0; m < 2; ++m)
#pragma unroll
      for (int i = 0; i < 4; ++i) {
        const int col = 64 * w + 16 * i + l16;
        const float bv = b0[col];
#pragma unroll
        for (int r = 0; r < 4; ++r)
          hs[(16 * m + quad * 4 + r) * 264 + col] = (bf16)fmaxf(acc[m][i][r] + bv, 0.0f);
      }
  }
  __syncthreads();

  // stage 2: x = relu(h @ W1^T + b1) + resid
  {
    f32x4 acc[2][4] = {};
#pragma unroll
    for (int ks = 0; ks < 8; ++ks) {
      bf16x8 af[2];
#pragma unroll
      for (int m = 0; m < 2; ++m)
        af[m] = *(const bf16x8*)&hs[(16 * m + l16) * 264 + ks * 32 + quad * 8];
      bf16x8 bw[4];
#pragma unroll
      for (int i = 0; i < 4; ++i) {
        const int col = 64 * w + 16 * i + l16;
        bw[i] = *(const bf16x8*)(W1 + (size_t)col * D_ + ks * 32 + quad * 8);
      }
#pragma unroll
      for (int m = 0; m < 2; ++m)
#pragma unroll
        for (int i = 0; i < 4; ++i) acc[m][i] = MFMA16(af[m], bw[i], acc[m][i]);
    }
#pragma unroll
    for (int m = 0; m < 2; ++m)
#pragma unroll
      for (int i = 0; i < 4; ++i) {
        const int d = 64 * w + 16 * i + l16;
        const float bv = b1[d];
        bf16x4 tv;
#pragma unroll
        for (int r = 0; r < 4; ++r) {
          const size_t R = (size_t)row0g + 16 * m + quad * 4 + r;
          float t = fmaxf(acc[m][i][r] + bv, 0.0f) + outX[R * D_ + d];
          outX[R * D_ + d] = t;
          xbo[R * D_ + d] = (bf16)t;
          tv[r] = (bf16)t;
        }
        *(bf16x4*)&xTo[((size_t)(b * D_ + d)) * N_ + node0 + 16 * m + quad * 4] = tv;
      }
  }
}

// ---------------------------------------------------------------------------
// final_proj: out = x @ Wf^T + bf (f32), per 32-row strip, B streamed.
// ---------------------------------------------------------------------------
__global__ __launch_bounds__(256, 4) void final_proj(
    const bf16* __restrict__ xin, const bf16* __restrict__ Wf,
    const float* __restrict__ bfv, float* __restrict__ outX)
{
  __shared__ bf16 as_[32 * 264];
  const int tid = threadIdx.x, w = tid >> 6, lane = tid & 63;
  const int l16 = lane & 15, quad = lane >> 4;
  const int row0g = blockIdx.x * 32;
#pragma unroll
  for (int e = 0; e < 4; ++e) {
    const int cc = tid + e * 256;
    const int r = cc >> 5, cg = cc & 31;
    *(bf16x8*)&as_[r * 264 + cg * 8] =
        *(const bf16x8*)(xin + ((size_t)(row0g + r)) * D_ + cg * 8);
  }
  __syncthreads();
  f32x4 acc[2][4] = {};
#pragma unroll
  for (int ks = 0; ks < 8; ++ks) {
    bf16x8 af[2];
#pragma unroll
    for (int m = 0; m < 2; ++m)
      af[m] = *(const bf16x8*)&as_[(16 * m + l16) * 264 + ks * 32 + quad * 8];
    bf16x8 bw[4];
#pragma unroll
    for (int i = 0; i < 4; ++i) {
      const int col = 64 * w + 16 * i + l16;
      bw[i] = *(const bf16x8*)(Wf + (size_t)col * D_ + ks * 32 + quad * 8);
    }
#pragma unroll
    for (int m = 0; m < 2; ++m)
#pragma unroll
      for (int i = 0; i < 4; ++i) acc[m][i] = MFMA16(af[m], bw[i], acc[m][i]);
  }
#pragma unroll
  for (int m = 0; m < 2; ++m)
#pragma unroll
    for (int i = 0; i < 4; ++i) {
      const int col = 64 * w + 16 * i + l16;
      const float bv = bfv[col];
#pragma unroll
      for (int r = 0; r < 4; ++r) {
        const size_t R = (size_t)row0g + 16 * m + quad * 4 + r;
        outX[R * D_ + col] = acc[m][i][r] + bv;
      }
    }
}

// ---------------------------------------------------------------------------
// init: x -> out_x (f32 master), x_bf16, xT_bf16 (LDS 32x32 transpose)
// ---------------------------------------------------------------------------
__global__ __launch_bounds__(256) void init_x(
    const float* __restrict__ x, float* __restrict__ outX,
    bf16* __restrict__ xb, bf16* __restrict__ xT)
{
  __shared__ float t[32 * 33];
  const int tid = threadIdx.x;
  const int nt = blockIdx.x, dt = blockIdx.y, b = blockIdx.z;
#pragma unroll
  for (int e = 0; e < 4; ++e) {
    const int idx = tid + e * 256;
    const int r = idx >> 5, c = idx & 31;
    const size_t g = ((size_t)(b * N_ + nt * 32 + r)) * D_ + dt * 32 + c;
    const float v = x[g];
    outX[g] = v;
    xb[g] = (bf16)v;
    t[r * 33 + c] = v;
  }
  __syncthreads();
#pragma unroll
  for (int e = 0; e < 4; ++e) {
    const int idx = tid + e * 256;
    const int r = idx >> 5, c = idx & 31;
    xT[((size_t)(b * D_ + dt * 32 + r)) * N_ + nt * 32 + c] = (bf16)t[c * 33 + r];
  }
}

__global__ __launch_bounds__(256) void cvt_bf16(
    const float* __restrict__ src, bf16* __restrict__ dst, int n4)
{
  const int i = blockIdx.x * 256 + threadIdx.x;
  if (i < n4) {
    const float4 v = ((const float4*)src)[i];
    bf16x4 o;
    o[0] = (bf16)v.x; o[1] = (bf16)v.y; o[2] = (bf16)v.z; o[3] = (bf16)v.w;
    ((bf16x4*)dst)[i] = o;
  }
}

extern "C" void kernel_launch(void* const* d_in, const int* in_sizes, int n_in,
                              void* d_out, int out_size, void* d_ws, size_t ws_size,
                              hipStream_t stream)
{
  const float* x_in  = (const float*)d_in[0];
  const float* adj   = (const float*)d_in[1];
  const float* wattn = (const float*)d_in[2];
  const float* battn = (const float*)d_in[3];
  const float* w0    = (const float*)d_in[4];
  const float* b0    = (const float*)d_in[5];
  const float* w1    = (const float*)d_in[6];
  const float* b1    = (const float*)d_in[7];
  const float* wf    = (const float*)d_in[8];
  const float* bfin  = (const float*)d_in[9];

  float* out_x    = (float*)d_out;                     // [B,N,D] f32 master
  float* out_attn = out_x + (size_t)B_ * N_ * D_;      // [L,B,N,N]

  bf16* wb = (bf16*)d_ws;                              // 13 * D*D weights
  bf16* xb = wb + 13 * (D_ * D_);                      // [B,N,D] bf16
  bf16* xT = xb + (size_t)B_ * N_ * D_;                // [B,D,N] bf16
  bf16* qb = xT + (size_t)B_ * N_ * D_;                // x' (attn output)

  const int DD2 = D_ * D_;
  const int Mfull = B_ * N_;  // 32768

  cvt_bf16<<<dim3((L_ * DD2 / 4 + 255) / 256), 256, 0, stream>>>(wattn, wb, L_ * DD2 / 4);
  cvt_bf16<<<dim3((L_ * DD2 / 4 + 255) / 256), 256, 0, stream>>>(w0, wb + 4 * DD2, L_ * DD2 / 4);
  cvt_bf16<<<dim3((L_ * DD2 / 4 + 255) / 256), 256, 0, stream>>>(w1, wb + 8 * DD2, L_ * DD2 / 4);
  cvt_bf16<<<dim3((DD2 / 4 + 255) / 256), 256, 0, stream>>>(wf, wb + 12 * DD2, DD2 / 4);

  init_x<<<dim3(N_ / 32, D_ / 32, B_), 256, 0, stream>>>(x_in, out_x, xb, xT);

  for (int l = 0; l < L_; ++l) {
    attn_layer<<<dim3(N_ / 32, B_), 256, 0, stream>>>(
        xb, xT, wb + l * DD2, battn + l * D_, adj,
        out_attn + (size_t)l * B_ * N_ * N_, qb);
    ffn_block<<<dim3(Mfull / 32), 256, 0, stream>>>(
        qb, wb + (4 + l) * DD2, b0 + l * D_,
        wb + (8 + l) * DD2, b1 + l * D_,
        out_x, xb, xT);
  }
  final_proj<<<dim3(Mfull / 32), 256, 0, stream>>>(xb, wb + 12 * DD2, bfin, out_x);
}

// Round 5
// 938.634 us; speedup vs baseline: 1.2713x; 1.1463x over previous
//
#include <hip/hip_runtime.h>
#include <cstdint>

#define B_ 64
#define N_ 512
#define D_ 256
#define L_ 4

typedef __bf16 bf16;
typedef __attribute__((ext_vector_type(8))) __bf16 bf16x8;
typedef __attribute__((ext_vector_type(4))) __bf16 bf16x4;
typedef __attribute__((ext_vector_type(4))) float f32x4;

#define MFMA16(a, b, c) __builtin_amdgcn_mfma_f32_16x16x32_bf16((a), (b), (c), 0, 0, 0)

__device__ __forceinline__ float sigmoidf_(float z) {
  return 1.0f / (1.0f + __expf(-z));
}

// ---------------------------------------------------------------------------
// gat_layer: one block per (32-row strip, batch); full layer fused:
//  p0: q = x@Wa^T+ba (Wa from L2)        p1: P = sigmoid(q@xb^T) masked (LDS)
//      adj from f32 (l=0, builds bitmask) or from 2MB bitmask (l>=1)
//  p2: rowsum -> normalize -> attls f32 out, P bf16 in LDS
//  p3: x' = P@x (xT from L2) -> LDS      p4: h = relu(x'@W0^T+b0) (LDS)
//  p5: x = relu(h@W1^T+b1) + resid(bf16) -> xb_out, xT_out
// Ping-pong xb/xT buffers: in-kernel blocks read xb_in while writing xb_out.
// LDS ~51.7 KB -> 3 blocks/CU.
// ---------------------------------------------------------------------------
__global__ __launch_bounds__(256, 3) void gat_layer(
    const bf16* __restrict__ xb_in, const bf16* __restrict__ xT_in,
    bf16* __restrict__ xb_out, bf16* __restrict__ xT_out,
    const bf16* __restrict__ Wa, const float* __restrict__ ba,
    const bf16* __restrict__ W0, const float* __restrict__ b0,
    const bf16* __restrict__ W1, const float* __restrict__ b1,
    const float* __restrict__ adj, const unsigned short* __restrict__ bits_in,
    unsigned short* __restrict__ bits_out, float* __restrict__ outA)
{
  __shared__ bf16 qs[32 * 264];     // q / x' strip (A-layout)
  __shared__ bf16 xps[32 * 520];    // x strip -> P -> h
  __shared__ float psum[4][32];
  __shared__ float rinvs[32];
  __shared__ unsigned int bits_s[512];  // 32 rows x 32 uint16 pieces

  const int tid = threadIdx.x, w = tid >> 6, lane = tid & 63;
  const int l16 = lane & 15, quad = lane >> 4;
  const int row0 = blockIdx.x * 32, b = blockIdx.y;

  // ---- stage x strip [32][256] -> xps (stride 264) ----
#pragma unroll
  for (int e = 0; e < 4; ++e) {
    const int cc = tid + e * 256;
    const int r = cc >> 5, cg = cc & 31;
    *(bf16x8*)&xps[r * 264 + cg * 8] =
        *(const bf16x8*)(xb_in + ((size_t)(b * N_ + row0 + r)) * D_ + cg * 8);
  }
  if (bits_in) {  // preload this strip's adjacency bitmask (2 KB)
#pragma unroll
    for (int e = 0; e < 2; ++e) {
      const int t = tid + e * 256;  // t = r*16 + k
      bits_s[t] = ((const unsigned int*)bits_in)[((size_t)b * N_ + row0) * 16 + t];
    }
  }
  __syncthreads();

  // ---- p0: q = x @ Wa^T + ba ; wave w -> cols [64w, 64w+64) ----
  {
    f32x4 acc0[2][4] = {};
#pragma unroll
    for (int ks = 0; ks < 8; ++ks) {
      bf16x8 af[2];
#pragma unroll
      for (int m = 0; m < 2; ++m)
        af[m] = *(const bf16x8*)&xps[(16 * m + l16) * 264 + ks * 32 + quad * 8];
      bf16x8 bw[4];
#pragma unroll
      for (int i = 0; i < 4; ++i) {
        const int col = 64 * w + 16 * i + l16;
        bw[i] = *(const bf16x8*)(Wa + (size_t)col * D_ + ks * 32 + quad * 8);
      }
#pragma unroll
      for (int m = 0; m < 2; ++m)
#pragma unroll
        for (int i = 0; i < 4; ++i) acc0[m][i] = MFMA16(af[m], bw[i], acc0[m][i]);
    }
    __syncthreads();  // xps x-copy still needed? no: only qs written below
#pragma unroll
    for (int m = 0; m < 2; ++m)
#pragma unroll
      for (int i = 0; i < 4; ++i) {
        const int col = 64 * w + 16 * i + l16;
        const float bv = ba[col];
#pragma unroll
        for (int r = 0; r < 4; ++r)
          qs[(16 * m + quad * 4 + r) * 264 + col] = (bf16)(acc0[m][i][r] + bv);
      }
  }
  __syncthreads();   // qs ready; xps (x strip) dead -> becomes P

  // ---- p1: P = sigmoid(q @ xb^T), diag/adj mask -> xps bf16 ----
  float p[2][4] = {};
  for (int ct = 0; ct < 4; ++ct) {
    f32x4 acc1[2][2] = {};
#pragma unroll
    for (int ks = 0; ks < 8; ++ks) {
      bf16x8 af[2];
#pragma unroll
      for (int m = 0; m < 2; ++m)
        af[m] = *(const bf16x8*)&qs[(16 * m + l16) * 264 + ks * 32 + quad * 8];
      bf16x8 bx[2];
#pragma unroll
      for (int jt = 0; jt < 2; ++jt) {
        const int gcol = ct * 128 + w * 32 + jt * 16 + l16;
        bx[jt] = *(const bf16x8*)(xb_in + ((size_t)(b * N_ + gcol)) * D_ + ks * 32 + quad * 8);
      }
#pragma unroll
      for (int m = 0; m < 2; ++m)
#pragma unroll
        for (int jt = 0; jt < 2; ++jt)
          acc1[m][jt] = MFMA16(af[m], bx[jt], acc1[m][jt]);
    }
#pragma unroll
    for (int jt = 0; jt < 2; ++jt) {
      const int lcol = ct * 128 + w * 32 + jt * 16 + l16;
      const int piece = ct * 8 + w * 2 + jt;
#pragma unroll
      for (int m = 0; m < 2; ++m)
#pragma unroll
        for (int r = 0; r < 4; ++r) {
          const int row = 16 * m + quad * 4 + r;
          const int grow = row0 + row;
          float av;
          if (bits_in) {
            const unsigned short m16 = ((const unsigned short*)bits_s)[row * 32 + piece];
            av = (float)((m16 >> l16) & 1);
          } else {
            av = adj[((size_t)b * N_ + grow) * N_ + lcol];
          }
          const bool diag = (grow == lcol);
          if (bits_out) {  // layer 0: build bitmask
            const unsigned long long bal = __ballot(diag || av != 0.0f);
            if (l16 == 0)
              bits_out[((size_t)b * N_ + row0 + 16 * m + 4 * quad + r) * 32 + piece] =
                  (unsigned short)((bal >> (quad * 16)) & 0xFFFFull);
          }
          const float sg = sigmoidf_(acc1[m][jt][r]);
          const float v = diag ? (sg + 1e-5f) : sg * av;
          const bf16 bv = (bf16)v;
          xps[row * 520 + lcol] = bv;
          p[m][r] += (float)bv;
        }
    }
  }
#pragma unroll
  for (int m = 0; m < 2; ++m)
#pragma unroll
    for (int r = 0; r < 4; ++r) {
#pragma unroll
      for (int msk = 1; msk < 16; msk <<= 1) p[m][r] += __shfl_xor(p[m][r], msk, 64);
    }
  if (l16 == 0) {
#pragma unroll
    for (int m = 0; m < 2; ++m)
#pragma unroll
      for (int r = 0; r < 4; ++r) psum[w][16 * m + quad * 4 + r] = p[m][r];
  }
  __syncthreads();
  if (tid < 32)
    rinvs[tid] = 1.0f / (psum[0][tid] + psum[1][tid] + psum[2][tid] + psum[3][tid]);
  __syncthreads();

  // ---- p2: normalize; attls f32 out; normalized bf16 back to xps ----
  const size_t abase = ((size_t)b * N_ + row0) * N_;
#pragma unroll
  for (int e = 0; e < 16; ++e) {
    const int idx = tid + e * 256;
    const int row = idx >> 7, c4 = (idx & 127) * 4;
    const float ri = rinvs[row];
    bf16x4 pv = *(const bf16x4*)&xps[row * 520 + c4];
    float4 nv;
    nv.x = (float)pv[0] * ri; nv.y = (float)pv[1] * ri;
    nv.z = (float)pv[2] * ri; nv.w = (float)pv[3] * ri;
    *(float4*)&outA[abase + (size_t)row * N_ + c4] = nv;
    bf16x4 o;
    o[0] = (bf16)nv.x; o[1] = (bf16)nv.y; o[2] = (bf16)nv.z; o[3] = (bf16)nv.w;
    *(bf16x4*)&xps[row * 520 + c4] = o;
  }
  __syncthreads();

  // ---- p3: x' = P @ x (B = xT streamed), K = 512 ----
  f32x4 acc3[2][4] = {};
#pragma unroll
  for (int ks = 0; ks < 16; ++ks) {
    bf16x8 af[2];
#pragma unroll
    for (int m = 0; m < 2; ++m)
      af[m] = *(const bf16x8*)&xps[(16 * m + l16) * 520 + ks * 32 + quad * 8];
    bf16x8 bt[4];
#pragma unroll
    for (int i = 0; i < 4; ++i) {
      const int d = 64 * w + 16 * i + l16;
      bt[i] = *(const bf16x8*)(xT_in + ((size_t)(b * D_ + d)) * N_ + ks * 32 + quad * 8);
    }
#pragma unroll
    for (int m = 0; m < 2; ++m)
#pragma unroll
      for (int i = 0; i < 4; ++i) acc3[m][i] = MFMA16(af[m], bt[i], acc3[m][i]);
  }
  __syncthreads();  // qs (q) dead -> x'
#pragma unroll
  for (int m = 0; m < 2; ++m)
#pragma unroll
    for (int i = 0; i < 4; ++i) {
      const int d = 64 * w + 16 * i + l16;
#pragma unroll
      for (int r = 0; r < 4; ++r)
        qs[(16 * m + quad * 4 + r) * 264 + d] = (bf16)acc3[m][i][r];
    }
  __syncthreads();

  // ---- p4: h = relu(x' @ W0^T + b0) -> xps (stride 264) ----
  {
    f32x4 acc[2][4] = {};
#pragma unroll
    for (int ks = 0; ks < 8; ++ks) {
      bf16x8 af[2];
#pragma unroll
      for (int m = 0; m < 2; ++m)
        af[m] = *(const bf16x8*)&qs[(16 * m + l16) * 264 + ks * 32 + quad * 8];
      bf16x8 bw[4];
#pragma unroll
      for (int i = 0; i < 4; ++i) {
        const int col = 64 * w + 16 * i + l16;
        bw[i] = *(const bf16x8*)(W0 + (size_t)col * D_ + ks * 32 + quad * 8);
      }
#pragma unroll
      for (int m = 0; m < 2; ++m)
#pragma unroll
        for (int i = 0; i < 4; ++i) acc[m][i] = MFMA16(af[m], bw[i], acc[m][i]);
    }
    __syncthreads();
#pragma unroll
    for (int m = 0; m < 2; ++m)
#pragma unroll
      for (int i = 0; i < 4; ++i) {
        const int col = 64 * w + 16 * i + l16;
        const float bv = b0[col];
#pragma unroll
        for (int r = 0; r < 4; ++r)
          xps[(16 * m + quad * 4 + r) * 264 + col] = (bf16)fmaxf(acc[m][i][r] + bv, 0.0f);
      }
  }
  __syncthreads();

  // ---- p5: x = relu(h @ W1^T + b1) + resid(bf16) -> xb_out, xT_out ----
  {
    f32x4 acc[2][4] = {};
#pragma unroll
    for (int ks = 0; ks < 8; ++ks) {
      bf16x8 af[2];
#pragma unroll
      for (int m = 0; m < 2; ++m)
        af[m] = *(const bf16x8*)&xps[(16 * m + l16) * 264 + ks * 32 + quad * 8];
      bf16x8 bw[4];
#pragma unroll
      for (int i = 0; i < 4; ++i) {
        const int col = 64 * w + 16 * i + l16;
        bw[i] = *(const bf16x8*)(W1 + (size_t)col * D_ + ks * 32 + quad * 8);
      }
#pragma unroll
      for (int m = 0; m < 2; ++m)
#pragma unroll
        for (int i = 0; i < 4; ++i) acc[m][i] = MFMA16(af[m], bw[i], acc[m][i]);
    }
#pragma unroll
    for (int m = 0; m < 2; ++m)
#pragma unroll
      for (int i = 0; i < 4; ++i) {
        const int d = 64 * w + 16 * i + l16;
        const float bv = b1[d];
        bf16x4 tv;
#pragma unroll
        for (int r = 0; r < 4; ++r) {
          const size_t R = (size_t)b * N_ + row0 + 16 * m + quad * 4 + r;
          const float x0 = (float)xb_in[R * D_ + d];
          const float t = fmaxf(acc[m][i][r] + bv, 0.0f) + x0;
          const bf16 tb = (bf16)t;
          xb_out[R * D_ + d] = tb;
          tv[r] = tb;
        }
        *(bf16x4*)&xT_out[((size_t)(b * D_ + d)) * N_ + row0 + 16 * m + quad * 4] = tv;
      }
  }
}

// ---------------------------------------------------------------------------
// final_proj: out = x @ Wf^T + bf (f32), per 32-row strip, B streamed.
// ---------------------------------------------------------------------------
__global__ __launch_bounds__(256, 4) void final_proj(
    const bf16* __restrict__ xin, const bf16* __restrict__ Wf,
    const float* __restrict__ bfv, float* __restrict__ outX)
{
  __shared__ bf16 as_[32 * 264];
  const int tid = threadIdx.x, w = tid >> 6, lane = tid & 63;
  const int l16 = lane & 15, quad = lane >> 4;
  const int row0g = blockIdx.x * 32;
#pragma unroll
  for (int e = 0; e < 4; ++e) {
    const int cc = tid + e * 256;
    const int r = cc >> 5, cg = cc & 31;
    *(bf16x8*)&as_[r * 264 + cg * 8] =
        *(const bf16x8*)(xin + ((size_t)(row0g + r)) * D_ + cg * 8);
  }
  __syncthreads();
  f32x4 acc[2][4] = {};
#pragma unroll
  for (int ks = 0; ks < 8; ++ks) {
    bf16x8 af[2];
#pragma unroll
    for (int m = 0; m < 2; ++m)
      af[m] = *(const bf16x8*)&as_[(16 * m + l16) * 264 + ks * 32 + quad * 8];
    bf16x8 bw[4];
#pragma unroll
    for (int i = 0; i < 4; ++i) {
      const int col = 64 * w + 16 * i + l16;
      bw[i] = *(const bf16x8*)(Wf + (size_t)col * D_ + ks * 32 + quad * 8);
    }
#pragma unroll
    for (int m = 0; m < 2; ++m)
#pragma unroll
      for (int i = 0; i < 4; ++i) acc[m][i] = MFMA16(af[m], bw[i], acc[m][i]);
  }
#pragma unroll
  for (int m = 0; m < 2; ++m)
#pragma unroll
    for (int i = 0; i < 4; ++i) {
      const int col = 64 * w + 16 * i + l16;
      const float bv = bfv[col];
#pragma unroll
      for (int r = 0; r < 4; ++r) {
        const size_t R = (size_t)row0g + 16 * m + quad * 4 + r;
        outX[R * D_ + col] = acc[m][i][r] + bv;
      }
    }
}

// ---------------------------------------------------------------------------
// init: x -> xb bf16, xT bf16 (LDS 32x32 transpose). No f32 master.
// ---------------------------------------------------------------------------
__global__ __launch_bounds__(256) void init_x(
    const float* __restrict__ x, bf16* __restrict__ xb, bf16* __restrict__ xT)
{
  __shared__ float t[32 * 33];
  const int tid = threadIdx.x;
  const int nt = blockIdx.x, dt = blockIdx.y, b = blockIdx.z;
#pragma unroll
  for (int e = 0; e < 4; ++e) {
    const int idx = tid + e * 256;
    const int r = idx >> 5, c = idx & 31;
    const size_t g = ((size_t)(b * N_ + nt * 32 + r)) * D_ + dt * 32 + c;
    const float v = x[g];
    xb[g] = (bf16)v;
    t[r * 33 + c] = v;
  }
  __syncthreads();
#pragma unroll
  for (int e = 0; e < 4; ++e) {
    const int idx = tid + e * 256;
    const int r = idx >> 5, c = idx & 31;
    xT[((size_t)(b * D_ + dt * 32 + r)) * N_ + nt * 32 + c] = (bf16)t[c * 33 + r];
  }
}

__global__ __launch_bounds__(256) void cvt_bf16(
    const float* __restrict__ src, bf16* __restrict__ dst, int n4)
{
  const int i = blockIdx.x * 256 + threadIdx.x;
  if (i < n4) {
    const float4 v = ((const float4*)src)[i];
    bf16x4 o;
    o[0] = (bf16)v.x; o[1] = (bf16)v.y; o[2] = (bf16)v.z; o[3] = (bf16)v.w;
    ((bf16x4*)dst)[i] = o;
  }
}

extern "C" void kernel_launch(void* const* d_in, const int* in_sizes, int n_in,
                              void* d_out, int out_size, void* d_ws, size_t ws_size,
                              hipStream_t stream)
{
  const float* x_in  = (const float*)d_in[0];
  const float* adj   = (const float*)d_in[1];
  const float* wattn = (const float*)d_in[2];
  const float* battn = (const float*)d_in[3];
  const float* w0    = (const float*)d_in[4];
  const float* b0    = (const float*)d_in[5];
  const float* w1    = (const float*)d_in[6];
  const float* b1    = (const float*)d_in[7];
  const float* wf    = (const float*)d_in[8];
  const float* bfin  = (const float*)d_in[9];

  float* out_x    = (float*)d_out;                     // [B,N,D] f32 (final only)
  float* out_attn = out_x + (size_t)B_ * N_ * D_;      // [L,B,N,N]

  const size_t XBN = (size_t)B_ * N_ * D_;
  bf16* wb  = (bf16*)d_ws;                             // 13 * D*D weights
  bf16* xb0 = wb + 13 * (D_ * D_);
  bf16* xT0 = xb0 + XBN;
  bf16* xb1 = xT0 + XBN;
  bf16* xT1 = xb1 + XBN;
  unsigned short* bits = (unsigned short*)(xT1 + XBN); // [B,N,32] uint16

  const int DD2 = D_ * D_;
  const int Mfull = B_ * N_;  // 32768

  cvt_bf16<<<dim3((L_ * DD2 / 4 + 255) / 256), 256, 0, stream>>>(wattn, wb, L_ * DD2 / 4);
  cvt_bf16<<<dim3((L_ * DD2 / 4 + 255) / 256), 256, 0, stream>>>(w0, wb + 4 * DD2, L_ * DD2 / 4);
  cvt_bf16<<<dim3((L_ * DD2 / 4 + 255) / 256), 256, 0, stream>>>(w1, wb + 8 * DD2, L_ * DD2 / 4);
  cvt_bf16<<<dim3((DD2 / 4 + 255) / 256), 256, 0, stream>>>(wf, wb + 12 * DD2, DD2 / 4);

  init_x<<<dim3(N_ / 32, D_ / 32, B_), 256, 0, stream>>>(x_in, xb0, xT0);

  bf16* xbs[2] = {xb0, xb1};
  bf16* xTs[2] = {xT0, xT1};
  for (int l = 0; l < L_; ++l) {
    const int pi = l & 1, po = 1 - pi;
    gat_layer<<<dim3(N_ / 32, B_), 256, 0, stream>>>(
        xbs[pi], xTs[pi], xbs[po], xTs[po],
        wb + l * DD2, battn + l * D_,
        wb + (4 + l) * DD2, b0 + l * D_,
        wb + (8 + l) * DD2, b1 + l * D_,
        adj, (l == 0) ? nullptr : bits, (l == 0) ? bits : nullptr,
        out_attn + (size_t)l * B_ * N_ * N_);
  }
  final_proj<<<dim3(Mfull / 32), 256, 0, stream>>>(xbs[0], wb + 12 * DD2, bfin, out_x);
}